// Round 1
// baseline (360.955 us; speedup 1.0000x reference)
//
#include <hip/hip_runtime.h>

typedef __attribute__((ext_vector_type(4))) float f32x4;
typedef __attribute__((ext_vector_type(8))) short s16x8;
typedef __attribute__((ext_vector_type(4))) short s16x4;

// B=2048 windows, N=64 tokens, C=256, H=32 heads, d=8
#define NWIN 2048
#define NTOK 64
#define CDIM 256
#define NHEAD 32

__device__ __forceinline__ ushort f2bf(float f) {
    union { float f; unsigned u; } v; v.f = f;
    unsigned r = v.u + 0x7FFFu + ((v.u >> 16) & 1u);   // RNE
    return (ushort)(r >> 16);
}
__device__ __forceinline__ float bf2f(ushort u) {
    union { unsigned u; float f; } v; v.u = ((unsigned)u) << 16;
    return v.f;
}

// ---- prep: weights -> bf16, bias_table gather -> bias[h][q][k] bf16 ----
__global__ void prep_kernel(const float* __restrict__ wqkv,
                            const float* __restrict__ wproj,
                            const float* __restrict__ btab,
                            ushort* __restrict__ wq,
                            ushort* __restrict__ wp,
                            ushort* __restrict__ bb) {
    int t = blockIdx.x * 256 + threadIdx.x;
    if (t < 196608) {                 // 768*256 w_qkv
        wq[t] = f2bf(wqkv[t]);
    } else if (t < 262144) {          // + 256*256 w_proj
        int i = t - 196608;
        wp[i] = f2bf(wproj[i]);
    } else if (t < 393216) {          // + 32*64*64 bias
        int i = t - 262144;
        int h  = i >> 12;
        int rem = i & 4095;
        int qi = rem >> 6;
        int kj = rem & 63;
        int rh = (qi >> 3) - (kj >> 3) + 7;
        int rw = (qi & 7)  - (kj & 7)  + 7;
        bb[i] = f2bf(btab[(rh * 15 + rw) * 32 + h]);
    }
}

// ---- fused: QKV gemm + head-norm + attention + proj, one block per window ----
__global__ __launch_bounds__(512, 2) void attn_kernel(
    const float* __restrict__ x,
    const float* __restrict__ bqkv,
    const float* __restrict__ bproj,
    const ushort* __restrict__ wq,
    const ushort* __restrict__ wp,
    const ushort* __restrict__ biasb,
    float* __restrict__ out)
{
    __shared__ ushort sQ [NHEAD * NTOK * 8];   // [h][n][d]    32 KB
    __shared__ ushort sK [NHEAD * NTOK * 8];   // [h][n][d]    32 KB
    __shared__ ushort sVT[NHEAD * 8 * NTOK];   // [h][d][n]    32 KB
    __shared__ ushort sX [NTOK * CDIM];        // x / inv-norm scratch / out_attn (aliased), 32 KB

    const int tid  = threadIdx.x;
    const int lane = tid & 63;
    const int w    = tid >> 6;      // wave 0..7
    const int g    = lane >> 4;     // 0..3
    const int c    = lane & 15;
    const int b    = blockIdx.x;

    const f32x4 fz = {0.f, 0.f, 0.f, 0.f};
    const s16x4 sz4 = {0, 0, 0, 0};

    // ================= phase 1: x -> bf16 LDS (row-XOR swizzled) =================
    {
        const float4* xg = (const float4*)(x + (size_t)b * (NTOK * CDIM));
        #pragma unroll
        for (int it = 0; it < 8; ++it) {
            int i = tid + it * 512;           // 4096 float4s
            float4 v = xg[i];
            int row = i >> 6;                 // 64 float4 per row
            int col = (i & 63) << 2;
            int bo = row * 512 + col * 2;
            bo ^= (row & 7) << 4;
            ushort4 u;
            u.x = f2bf(v.x); u.y = f2bf(v.y); u.z = f2bf(v.z); u.w = f2bf(v.w);
            *(ushort4*)((char*)sX + bo) = u;
        }
    }
    __syncthreads();

    // ================= phase 2: QKV GEMM (M=64, N=768, K=256) =================
    {
        f32x4 acc[4][6];
        #pragma unroll
        for (int mi = 0; mi < 4; ++mi)
            #pragma unroll
            for (int nj = 0; nj < 6; ++nj) acc[mi][nj] = fz;

        #pragma unroll
        for (int ks = 0; ks < 8; ++ks) {
            s16x8 af[4];
            #pragma unroll
            for (int mi = 0; mi < 4; ++mi) {
                int row = 16 * mi + c;
                int bo = row * 512 + ks * 64 + g * 16;
                bo ^= (row & 7) << 4;
                af[mi] = *(const s16x8*)((const char*)sX + bo);
            }
            s16x8 wfr[6];
            #pragma unroll
            for (int nj = 0; nj < 6; ++nj) {
                int col = 96 * w + 16 * nj + c;
                wfr[nj] = *(const s16x8*)(wq + col * 256 + ks * 32 + g * 8);
            }
            #pragma unroll
            for (int mi = 0; mi < 4; ++mi)
                #pragma unroll
                for (int nj = 0; nj < 6; ++nj)
                    acc[mi][nj] = __builtin_amdgcn_mfma_f32_16x16x32_bf16(
                        af[mi], wfr[nj], acc[mi][nj], 0, 0, 0);
        }

        // epilogue: +bias, scatter to sQ / sK / sVT (V transposed)
        #pragma unroll
        for (int nj = 0; nj < 6; ++nj) {
            int col   = 96 * w + 16 * nj + c;
            int which = col >> 8;            // 0=q 1=k 2=v (uniform per tile)
            int hh    = (col >> 3) & 31;
            int dd    = col & 7;
            float bias = bqkv[col];
            #pragma unroll
            for (int mi = 0; mi < 4; ++mi) {
                #pragma unroll
                for (int j = 0; j < 4; ++j) {
                    int m = 16 * mi + 4 * g + j;
                    ushort bv = f2bf(acc[mi][nj][j] + bias);
                    if (which == 0)      sQ [(hh * 64 + m) * 8 + dd] = bv;
                    else if (which == 1) sK [(hh * 64 + m) * 8 + dd] = bv;
                    else                 sVT[(hh * 8 + dd) * 64 + m] = bv;
                }
            }
        }
    }
    __syncthreads();

    // ============ phase 2.5: head-axis norm quirk (per (n,d) across 32 heads) ============
    {
        float* sInv = (float*)sX;            // x is dead; 4 KB scratch
        int n = tid >> 3, dd = tid & 7;
        float sq = 0.f, sk = 0.f;
        #pragma unroll 8
        for (int h = 0; h < 32; ++h) {
            float qv = bf2f(sQ[(h * 64 + n) * 8 + dd]);
            float kv = bf2f(sK[(h * 64 + n) * 8 + dd]);
            sq += qv * qv;
            sk += kv * kv;
        }
        sInv[tid]       = 1.f / fmaxf(sqrtf(sq), 1e-12f);
        sInv[512 + tid] = 1.f / fmaxf(sqrtf(sk), 1e-12f);
        __syncthreads();
        for (int r = tid; r < 2048; r += 512) {   // 32*64 (h,n) rows
            int h = r >> 6, nn = r & 63;
            ushort* qp = sQ + (h * 64 + nn) * 8;
            ushort* kp = sK + (h * 64 + nn) * 8;
            const float* iq = sInv + nn * 8;
            const float* ik = sInv + 512 + nn * 8;
            #pragma unroll
            for (int d2 = 0; d2 < 8; ++d2) {
                qp[d2] = f2bf(bf2f(qp[d2]) * iq[d2]);
                kp[d2] = f2bf(bf2f(kp[d2]) * ik[d2]);
            }
        }
    }
    __syncthreads();

    // ================= phase 3: attention, wave w -> heads 4w..4w+3 =================
    {
        #pragma unroll 1
        for (int hi = 0; hi < 4; ++hi) {
            int h = w * 4 + hi;
            // K (A) and Q (B) fragments; contraction dim = d = 8 of 16 (lanes g>=2 zero)
            s16x4 kf[4], qf[4];
            #pragma unroll
            for (int t = 0; t < 4; ++t) {
                if (g < 2) {
                    kf[t] = *(const s16x4*)(sK + (h * 64 + 16 * t + c) * 8 + g * 4);
                    qf[t] = *(const s16x4*)(sQ + (h * 64 + 16 * t + c) * 8 + g * 4);
                } else { kf[t] = sz4; qf[t] = sz4; }
            }
            // S^T = K * Q^T  -> lane holds S[q=16tq+c][k=16tk+4g+j]
            f32x4 S[4][4];
            #pragma unroll
            for (int tk = 0; tk < 4; ++tk)
                #pragma unroll
                for (int tq = 0; tq < 4; ++tq)
                    S[tk][tq] = __builtin_amdgcn_mfma_f32_16x16x16bf16_1k(
                        kf[tk], qf[tq], fz, 0, 0, 0);

            // + bias, exp (|logit|<=~8, no max-sub needed), row sums
            const ushort* bh = biasb + h * 4096;   // [q][k]
            float rinv[4];
            #pragma unroll
            for (int tq = 0; tq < 4; ++tq) {
                float sum = 0.f;
                #pragma unroll
                for (int tk = 0; tk < 4; ++tk) {
                    ushort4 bv4 = *(const ushort4*)(bh + (16 * tq + c) * 64 + 16 * tk + 4 * g);
                    float e0 = __expf(S[tk][tq][0] + bf2f(bv4.x));
                    float e1 = __expf(S[tk][tq][1] + bf2f(bv4.y));
                    float e2 = __expf(S[tk][tq][2] + bf2f(bv4.z));
                    float e3 = __expf(S[tk][tq][3] + bf2f(bv4.w));
                    S[tk][tq][0] = e0; S[tk][tq][1] = e1;
                    S[tk][tq][2] = e2; S[tk][tq][3] = e3;
                    sum += e0 + e1 + e2 + e3;
                }
                sum += __shfl_xor(sum, 16);
                sum += __shfl_xor(sum, 32);
                rinv[tq] = 1.f / sum;
            }

            // V fragments (B operand): V[k][d] from sVT[h][d][k]
            s16x4 vf[4];
            #pragma unroll
            for (int kv = 0; kv < 4; ++kv) {
                if (c < 8) vf[kv] = *(const s16x4*)(sVT + (h * 8 + c) * 64 + 16 * kv + 4 * g);
                else vf[kv] = sz4;
            }
            // PV: P regs feed A-fragments directly (swapped-QK layout identity)
            f32x4 o[4];
            #pragma unroll
            for (int tq = 0; tq < 4; ++tq) o[tq] = fz;
            #pragma unroll
            for (int tq = 0; tq < 4; ++tq) {
                #pragma unroll
                for (int kv = 0; kv < 4; ++kv) {
                    s16x4 pa;
                    pa[0] = (short)f2bf(S[kv][tq][0] * rinv[tq]);
                    pa[1] = (short)f2bf(S[kv][tq][1] * rinv[tq]);
                    pa[2] = (short)f2bf(S[kv][tq][2] * rinv[tq]);
                    pa[3] = (short)f2bf(S[kv][tq][3] * rinv[tq]);
                    o[tq] = __builtin_amdgcn_mfma_f32_16x16x16bf16_1k(pa, vf[kv], o[tq], 0, 0, 0);
                }
            }
            // out_attn[q][h*8+d] -> sX (swizzled, d = c < 8; row m = 4g+j)
            if (c < 8) {
                #pragma unroll
                for (int tq = 0; tq < 4; ++tq) {
                    #pragma unroll
                    for (int j = 0; j < 4; ++j) {
                        int q = 16 * tq + 4 * g + j;
                        int bo = q * 512 + (h * 8 + c) * 2;
                        bo ^= (q & 7) << 4;
                        *(ushort*)((char*)sX + bo) = f2bf(o[tq][j]);
                    }
                }
            }
        }
    }
    __syncthreads();

    // ================= phase 4: proj GEMM (M=64, N=256, K=256) + bias =================
    {
        f32x4 pacc[4][2];
        #pragma unroll
        for (int mi = 0; mi < 4; ++mi) { pacc[mi][0] = fz; pacc[mi][1] = fz; }

        #pragma unroll
        for (int ks = 0; ks < 8; ++ks) {
            s16x8 af[4];
            #pragma unroll
            for (int mi = 0; mi < 4; ++mi) {
                int row = 16 * mi + c;
                int bo = row * 512 + ks * 64 + g * 16;
                bo ^= (row & 7) << 4;
                af[mi] = *(const s16x8*)((const char*)sX + bo);
            }
            s16x8 wfr[2];
            #pragma unroll
            for (int nj = 0; nj < 2; ++nj) {
                int col = 32 * w + 16 * nj + c;
                wfr[nj] = *(const s16x8*)(wp + col * 256 + ks * 32 + g * 8);
            }
            #pragma unroll
            for (int mi = 0; mi < 4; ++mi)
                #pragma unroll
                for (int nj = 0; nj < 2; ++nj)
                    pacc[mi][nj] = __builtin_amdgcn_mfma_f32_16x16x32_bf16(
                        af[mi], wfr[nj], pacc[mi][nj], 0, 0, 0);
        }

        float* og = out + (size_t)b * (NTOK * CDIM);
        #pragma unroll
        for (int nj = 0; nj < 2; ++nj) {
            int col = 32 * w + 16 * nj + c;
            float bp = bproj[col];
            #pragma unroll
            for (int mi = 0; mi < 4; ++mi) {
                #pragma unroll
                for (int j = 0; j < 4; ++j) {
                    int row = 16 * mi + 4 * g + j;
                    og[row * 256 + col] = pacc[mi][nj][j] + bp;
                }
            }
        }
    }
}

extern "C" void kernel_launch(void* const* d_in, const int* in_sizes, int n_in,
                              void* d_out, int out_size, void* d_ws, size_t ws_size,
                              hipStream_t stream) {
    const float* x     = (const float*)d_in[0];
    const float* wqkv  = (const float*)d_in[1];
    const float* bqkv  = (const float*)d_in[2];
    const float* wproj = (const float*)d_in[3];
    const float* bproj = (const float*)d_in[4];
    const float* btab  = (const float*)d_in[5];

    ushort* wq_b   = (ushort*)d_ws;           // 768*256   = 196608 bf16
    ushort* wp_b   = wq_b + 196608;           // 256*256   =  65536 bf16
    ushort* bias_b = wp_b + 65536;            // 32*64*64  = 131072 bf16 (total 768 KB)

    prep_kernel<<<1536, 256, 0, stream>>>(wqkv, wproj, btab, wq_b, wp_b, bias_b);
    attn_kernel<<<NWIN, 512, 0, stream>>>(x, bqkv, bproj, wq_b, wp_b, bias_b,
                                          (float*)d_out);
}